// Round 3
// baseline (2579.267 us; speedup 1.0000x reference)
//
#include <hip/hip_runtime.h>
#include <hip/hip_bf16.h>

#define TT    1024
#define BATCH 512
#define HH    128
#define II    64
#define BCG   16    // batch samples per group
#define NTHR  1024  // 16 waves: waves 0-7 = group A, 8-15 = group B
#define GTHR  512
#define CHUNK 4
#define XROW  72    // shorts per x row: 64 data + 8 pad
#define HROW  136   // shorts per h row: 128 data + 8 pad

typedef __attribute__((ext_vector_type(8))) short bhalf8;
typedef __attribute__((ext_vector_type(4))) short bhalf4;
typedef __attribute__((ext_vector_type(4))) float f32x4;

static __device__ __forceinline__ unsigned pack2bf(float lo, float hi) {
  unsigned a = (unsigned)__builtin_bit_cast(unsigned short, __float2bfloat16(lo));
  unsigned b = (unsigned)__builtin_bit_cast(unsigned short, __float2bfloat16(hi));
  return a | (b << 16);
}
static __device__ __forceinline__ float bf2f(short s) {
  return __builtin_bit_cast(float, ((unsigned)(unsigned short)s) << 16);
}
static __device__ __forceinline__ f32x4 mfma16(bhalf8 a, bhalf8 b, f32x4 c) {
  return __builtin_amdgcn_mfma_f32_16x16x32_bf16(a, b, c, 0, 0, 0);
}
static __device__ __forceinline__ bhalf8 packrow8(const float* p) {
  union { bhalf8 v; unsigned u[4]; } cv;
  cv.u[0] = pack2bf(p[0], p[1]);
  cv.u[1] = pack2bf(p[2], p[3]);
  cv.u[2] = pack2bf(p[4], p[5]);
  cv.u[3] = pack2bf(p[6], p[7]);
  return cv.v;
}
// barrier without vmcnt drain (x prefetch stays in flight); lgkmcnt(0) orders LDS.
static __device__ __forceinline__ void bar_lgkm() {
  asm volatile("s_waitcnt lgkmcnt(0)\n\ts_barrier" ::: "memory");
}

// Two phase-skewed 16-sample groups per 1024-thread WG. Each SIMD holds
// 2 group-A waves + 2 group-B waves; A does MFMA-span while B does gate-span
// and vice versa -> matrix and VALU pipes overlap (they serialized before).
// Divergent-barrier pattern: both groups execute exactly 2 bar_lgkm per step.
__global__ __launch_bounds__(NTHR, 1) void gru_fused(
    const float* __restrict__ xin, const float* __restrict__ Wih,
    const float* __restrict__ Whh, const float* __restrict__ bih,
    const float* __restrict__ bhh, const float* __restrict__ Wfc,
    const float* __restrict__ bfc, float* __restrict__ out)
{
  __shared__ short xsh[2][2][CHUNK][BCG * XROW];  // [group][dbuf][step][sample*XROW]
  __shared__ short hsh[2][2][BCG * HROW];         // [group][parity][sample*HROW]
  __shared__ float bsh[4][HH];                    // r,z,hn,xn bias (broadcast reads)

  const int tid  = threadIdx.x;
  const int grp  = tid >> 9;
  const int t9   = tid & (GTHR - 1);
  const int lane = tid & 63;
  const int wv   = t9 >> 6;      // wave within group: 0..7 -> h-dims [wv*16, wv*16+16)
  const int q    = lane >> 4;
  const int c15  = lane & 15;
  const int bblk = blockIdx.x * (2 * BCG);
  const int b0   = bblk + grp * BCG;

  // ---- resident weight fragments (A-operand layout) ----
  bhalf8 whh[3][4];
  bhalf8 wih[3][2];
#pragma unroll
  for (int g = 0; g < 3; ++g) {
    const int grow = g * HH + wv * 16 + c15;
#pragma unroll
    for (int kt = 0; kt < 4; ++kt)
      whh[g][kt] = packrow8(Whh + grow * HH + kt * 32 + q * 8);
#pragma unroll
    for (int kt = 0; kt < 2; ++kt)
      wih[g][kt] = packrow8(Wih + grow * II + kt * 32 + q * 8);
  }

  // biases -> LDS (saves 16 VGPRs vs register-resident; reads are broadcast)
  if (tid < HH) {
    bsh[0][tid] = bih[tid] + bhh[tid];
    bsh[1][tid] = bih[HH + tid] + bhh[HH + tid];
    bsh[2][tid] = bhh[2 * HH + tid];
    bsh[3][tid] = bih[2 * HH + tid];
  }
  for (int i = t9; i < BCG * HROW; i += GTHR) hsh[grp][0][i] = 0;

  // ---- stage chunk 0 (steps 0..3) ----
  const int tp0 = t9 >> 7, bs = (t9 >> 3) & 15, g8 = t9 & 7;
  const float* xsrc = xin + (size_t)(b0 + bs) * (TT * II) + g8 * 8;
  {
    float4 a = *(const float4*)(xsrc + tp0 * II);
    float4 b = *(const float4*)(xsrc + tp0 * II + 4);
    union { bhalf8 v; unsigned u[4]; } cv;
    cv.u[0] = pack2bf(a.x, a.y); cv.u[1] = pack2bf(a.z, a.w);
    cv.u[2] = pack2bf(b.x, b.y); cv.u[3] = pack2bf(b.z, b.w);
    *(bhalf8*)&xsh[grp][0][tp0][bs * XROW + g8 * 8] = cv.v;
  }
  __syncthreads();

  const short* hrd0 = &hsh[grp][0][c15 * HROW];
  const short* hrd1 = &hsh[grp][1][c15 * HROW];
  short* hw0 = &hsh[grp][1][c15 * HROW + wv * 16 + q * 4];  // write when t even
  short* hw1 = &hsh[grp][0][c15 * HROW + wv * 16 + q * 4];  // write when t odd
  const float* bRp  = &bsh[0][wv * 16 + q * 4];
  const float* bZp  = &bsh[1][wv * 16 + q * 4];
  const float* bHNp = &bsh[2][wv * 16 + q * 4];
  const float* bXNp = &bsh[3][wv * 16 + q * 4];

  f32x4 ar, az, ahn, axn;
  f32x4 hprev = {0.f, 0.f, 0.f, 0.f};
  float4 xla, xlb;

  // acc <- bias + x-side MFMAs for step t
  auto ACCINIT = [&](int t) {
    ar  = *(const f32x4*)bRp;
    az  = *(const f32x4*)bZp;
    ahn = *(const f32x4*)bHNp;
    axn = *(const f32x4*)bXNp;
    const short* xrow = &xsh[grp][(t >> 2) & 1][t & 3][c15 * XROW];
    bhalf8 xf0 = *(const bhalf8*)(xrow + q * 8);
    bhalf8 xf1 = *(const bhalf8*)(xrow + 32 + q * 8);
    ar  = mfma16(wih[0][0], xf0, ar);  ar  = mfma16(wih[0][1], xf1, ar);
    az  = mfma16(wih[1][0], xf0, az);  az  = mfma16(wih[1][1], xf1, az);
    axn = mfma16(wih[2][0], xf0, axn); axn = mfma16(wih[2][1], xf1, axn);
  };

  // h-read + 12 h-side MFMAs for step t
  auto RM = [&](int t) {
    const short* hrow = (t & 1) ? hrd1 : hrd0;
    bhalf8 hf0 = *(const bhalf8*)(hrow + q * 8);
    bhalf8 hf1 = *(const bhalf8*)(hrow + 32 + q * 8);
    bhalf8 hf2 = *(const bhalf8*)(hrow + 64 + q * 8);
    bhalf8 hf3 = *(const bhalf8*)(hrow + 96 + q * 8);
    ar  = mfma16(whh[0][0], hf0, ar);  ar  = mfma16(whh[0][1], hf1, ar);
    ar  = mfma16(whh[0][2], hf2, ar);  ar  = mfma16(whh[0][3], hf3, ar);
    az  = mfma16(whh[1][0], hf0, az);  az  = mfma16(whh[1][1], hf1, az);
    az  = mfma16(whh[1][2], hf2, az);  az  = mfma16(whh[1][3], hf3, az);
    ahn = mfma16(whh[2][0], hf0, ahn); ahn = mfma16(whh[2][1], hf1, ahn);
    ahn = mfma16(whh[2][2], hf2, ahn); ahn = mfma16(whh[2][3], hf3, ahn);
  };

  // gates + h-write + x staging + acc-init for t+1
  auto GW = [&](int t) {
    if ((t & 3) == 0 && t + 4 < TT) {  // issue next-chunk loads (land 2 steps later)
      xla = *(const float4*)(xsrc + (t + 4 + tp0) * II);
      xlb = *(const float4*)(xsrc + (t + 4 + tp0) * II + 4);
    }
#pragma unroll
    for (int r = 0; r < 4; ++r) {
      const float rg = __builtin_amdgcn_rcpf(1.0f + __expf(-ar[r]));
      const float zg = __builtin_amdgcn_rcpf(1.0f + __expf(-az[r]));
      const float na = fmaf(rg, ahn[r], axn[r]);
      const float e2 = __expf(na + na);
      const float ng = fmaf(-2.0f, __builtin_amdgcn_rcpf(e2 + 1.0f), 1.0f);
      hprev[r] = fmaf(zg, hprev[r] - ng, ng);
    }
    union { bhalf4 v; unsigned u[2]; } hp;
    hp.u[0] = pack2bf(hprev[0], hprev[1]);
    hp.u[1] = pack2bf(hprev[2], hprev[3]);
    *(bhalf4*)((t & 1) ? hw1 : hw0) = hp.v;

    if ((t & 3) == 2 && t + 2 < TT) {  // write staged chunk into other x buffer
      union { bhalf8 v; unsigned u[4]; } cv;
      cv.u[0] = pack2bf(xla.x, xla.y); cv.u[1] = pack2bf(xla.z, xla.w);
      cv.u[2] = pack2bf(xlb.x, xlb.y); cv.u[3] = pack2bf(xlb.z, xlb.w);
      *(bhalf8*)&xsh[grp][((t + 2) >> 2) & 1][tp0][bs * XROW + g8 * 8] = cv.v;
    }
    if (t + 1 < TT) ACCINIT(t + 1);
  };

  ACCINIT(0);
  if (grp == 0) {
    // A: [R+M(t)] bar [G+W(t)] bar
#pragma unroll 4
    for (int t = 0; t < TT; ++t) {
      RM(t); bar_lgkm();
      GW(t); bar_lgkm();
    }
  } else {
    // B (skewed one span): prologue R+M(0); [G+W(t)] bar [R+M(t+1)] bar
    RM(0);
#pragma unroll 4
    for (int t = 0; t < TT; ++t) {
      GW(t); bar_lgkm();
      if (t + 1 < TT) RM(t + 1);
      bar_lgkm();
    }
  }
  __syncthreads();

  // ---- FC head: 32 samples x 51 outputs; h_T in hsh[g][0] ----
  for (int idx = tid; idx < 2 * BCG * 51; idx += NTHR) {
    const int s = idx / 51;
    const int o = idx - s * 51;
    const int gs = s >> 4, bb = s & 15;
    const float* wf = Wfc + o * HH;
    const short* hr = &hsh[gs][0][bb * HROW];
    float acc = bfc[o];
#pragma unroll
    for (int d = 0; d < HH; d += 4) {
      const float4 wvv = *(const float4*)(wf + d);
      acc += bf2f(hr[d]) * wvv.x + bf2f(hr[d + 1]) * wvv.y
           + bf2f(hr[d + 2]) * wvv.z + bf2f(hr[d + 3]) * wvv.w;
    }
    out[(size_t)(bblk + s) * 51 + o] = acc;
  }
}

extern "C" void kernel_launch(void* const* d_in, const int* in_sizes, int n_in,
                              void* d_out, int out_size, void* d_ws, size_t ws_size,
                              hipStream_t stream) {
  const float* xin = (const float*)d_in[0];
  const float* Wih = (const float*)d_in[1];
  const float* Whh = (const float*)d_in[2];
  const float* bih = (const float*)d_in[3];
  const float* bhh = (const float*)d_in[4];
  const float* Wfc = (const float*)d_in[5];
  const float* bfc = (const float*)d_in[6];
  float* o = (float*)d_out;
  hipLaunchKernelGGL(gru_fused, dim3(BATCH / (2 * BCG)), dim3(NTHR), 0, stream,
                     xin, Wih, Whh, bih, bhh, Wfc, bfc, o);
}

// Round 4
// 608.740 us; speedup vs baseline: 4.2371x; 4.2371x over previous
//
#include <hip/hip_runtime.h>
#include <hip/hip_bf16.h>

#define TT    1024
#define BATCH 512
#define HH    128
#define II    64
#define BC    16
#define NTHR  512
#define CHUNK 8
#define XROW  72   // shorts per x row: 64 data + 8 pad
#define HROW  136  // shorts per h row: 128 data + 8 pad
#define L2E   1.4426950408889634f

typedef __attribute__((ext_vector_type(8))) short bhalf8;
typedef __attribute__((ext_vector_type(4))) short bhalf4;
typedef __attribute__((ext_vector_type(4))) float f32x4;

// packed RNE f32->2xbf16 in one instruction (D.lo=S0, D.hi=S1)
static __device__ __forceinline__ unsigned cvtpk(float lo, float hi) {
  unsigned r;
  asm("v_cvt_pk_bf16_f32 %0, %1, %2" : "=v"(r) : "v"(lo), "v"(hi));
  return r;
}
static __device__ __forceinline__ float bf2f(short s) {
  return __builtin_bit_cast(float, ((unsigned)(unsigned short)s) << 16);
}
static __device__ __forceinline__ f32x4 mfma16(bhalf8 a, bhalf8 b, f32x4 c) {
  return __builtin_amdgcn_mfma_f32_16x16x32_bf16(a, b, c, 0, 0, 0);
}
static __device__ __forceinline__ bhalf8 packrow8s(const float* p, float s) {
  union { bhalf8 v; unsigned u[4]; } cv;
  cv.u[0] = cvtpk(p[0] * s, p[1] * s);
  cv.u[1] = cvtpk(p[2] * s, p[3] * s);
  cv.u[2] = cvtpk(p[4] * s, p[5] * s);
  cv.u[3] = cvtpk(p[6] * s, p[7] * s);
  return cv.v;
}
// barrier without vmcnt drain (x prefetch stays in flight); lgkmcnt(0) orders LDS
static __device__ __forceinline__ void bar_lgkm() {
  asm volatile("s_waitcnt lgkmcnt(0)\n\ts_barrier" ::: "memory");
}

// One step: consume acc set {AR,AZ,AHN,AXN} (holds bias + x-MFMAs for step t),
// refill set {BR,BZ,BHN,BXN} for t+1. x-MFMAs for t+1 issue BEFORE gates(t) so
// their pipe time hides under gate VALU. One lgkm barrier per step.
#define DOSTEP(TP, AR, AZ, AHN, AXN, BR, BZ, BHN, BXN)                          \
  {                                                                             \
    constexpr int tp = (TP);                                                    \
    const short* hrow = (tp & 1) ? hrd1 : hrd0;                                 \
    bhalf8 hf0 = *(const bhalf8*)(hrow + q * 8);                                \
    bhalf8 hf1 = *(const bhalf8*)(hrow + 32 + q * 8);                           \
    bhalf8 hf2 = *(const bhalf8*)(hrow + 64 + q * 8);                           \
    bhalf8 hf3 = *(const bhalf8*)(hrow + 96 + q * 8);                           \
    if (tp == 0 && more) { /* issue next-chunk global loads (land by tp==4) */  \
      const float* sA = xsrcA + (size_t)(c + 1) * (CHUNK * II);                 \
      xl0 = *(const float4*)(sA);                                               \
      xl1 = *(const float4*)(sA + 4);                                           \
      xl2 = *(const float4*)(sA + 4 * II);                                      \
      xl3 = *(const float4*)(sA + 4 * II + 4);                                  \
    }                                                                           \
    AR  = mfma16(whh[0][0], hf0, AR);  AR  = mfma16(whh[0][1], hf1, AR);        \
    AR  = mfma16(whh[0][2], hf2, AR);  AR  = mfma16(whh[0][3], hf3, AR);        \
    AZ  = mfma16(whh[1][0], hf0, AZ);  AZ  = mfma16(whh[1][1], hf1, AZ);        \
    AZ  = mfma16(whh[1][2], hf2, AZ);  AZ  = mfma16(whh[1][3], hf3, AZ);        \
    AHN = mfma16(whh[2][0], hf0, AHN); AHN = mfma16(whh[2][1], hf1, AHN);       \
    AHN = mfma16(whh[2][2], hf2, AHN); AHN = mfma16(whh[2][3], hf3, AHN);       \
    /* refill for t+1 (reads only x LDS + bias; independent of h(t)) */         \
    {                                                                           \
      const int nb2 = (tp == 7) ? ((c + 1) & 1) : (c & 1);                      \
      const short* xrow = xbase + nb2 * (CHUNK * BC * XROW)                     \
                                + ((tp + 1) & 7) * (BC * XROW);                 \
      bhalf8 xf0 = *(const bhalf8*)(xrow + q * 8);                              \
      bhalf8 xf1 = *(const bhalf8*)(xrow + 32 + q * 8);                         \
      BR  = bias_r;                                                             \
      BR  = mfma16(wih[0][0], xf0, BR);  BR  = mfma16(wih[0][1], xf1, BR);      \
      BZ  = bias_z;                                                             \
      BZ  = mfma16(wih[1][0], xf0, BZ);  BZ  = mfma16(wih[1][1], xf1, BZ);      \
      BXN = bias_xn;                                                            \
      BXN = mfma16(wih[2][0], xf0, BXN); BXN = mfma16(wih[2][1], xf1, BXN);     \
      BHN = bias_hn;                                                            \
    }                                                                           \
    /* gates (exp2 domain: weights prescaled by log2e / 2log2e) */              \
    _Pragma("unroll")                                                           \
    for (int r = 0; r < 4; ++r) {                                               \
      const float rg = __builtin_amdgcn_rcpf(                                   \
          1.0f + __builtin_amdgcn_exp2f(-AR[r]));                               \
      const float zg = __builtin_amdgcn_rcpf(                                   \
          1.0f + __builtin_amdgcn_exp2f(-AZ[r]));                               \
      const float na = fmaf(rg, AHN[r], AXN[r]);                                \
      const float ng = fmaf(-2.0f, __builtin_amdgcn_rcpf(                       \
          __builtin_amdgcn_exp2f(na) + 1.0f), 1.0f);                            \
      hprev[r] = fmaf(zg, hprev[r] - ng, ng);                                   \
    }                                                                           \
    {                                                                           \
      union { bhalf4 v; unsigned u[2]; } hp;                                    \
      hp.u[0] = cvtpk(hprev[0], hprev[1]);                                      \
      hp.u[1] = cvtpk(hprev[2], hprev[3]);                                      \
      *(bhalf4*)((tp & 1) ? hw1 : hw0) = hp.v;                                  \
    }                                                                           \
    if (tp == 4 && more) { /* write staged chunk into other x buffer */         \
      short* xd = xstA + ((c + 1) & 1) * (CHUNK * BC * XROW);                   \
      union { bhalf8 v; unsigned u[4]; } cv;                                    \
      cv.u[0] = cvtpk(xl0.x, xl0.y); cv.u[1] = cvtpk(xl0.z, xl0.w);             \
      cv.u[2] = cvtpk(xl1.x, xl1.y); cv.u[3] = cvtpk(xl1.z, xl1.w);             \
      *(bhalf8*)xd = cv.v;                                                      \
      cv.u[0] = cvtpk(xl2.x, xl2.y); cv.u[1] = cvtpk(xl2.z, xl2.w);             \
      cv.u[2] = cvtpk(xl3.x, xl3.y); cv.u[3] = cvtpk(xl3.z, xl3.w);             \
      *(bhalf8*)(xd + 4 * (BC * XROW)) = cv.v;                                  \
    }                                                                           \
    bar_lgkm();                                                                 \
  }

__global__ __launch_bounds__(NTHR) __attribute__((amdgpu_waves_per_eu(2, 2)))
void gru_fused(
    const float* __restrict__ xin, const float* __restrict__ Wih,
    const float* __restrict__ Whh, const float* __restrict__ bih,
    const float* __restrict__ bhh, const float* __restrict__ Wfc,
    const float* __restrict__ bfc, float* __restrict__ out)
{
  __shared__ short xsh[2][CHUNK][BC * XROW];
  __shared__ short hsh[2][BC * HROW];

  const int tid = threadIdx.x;
  const int lane = tid & 63;
  const int wv = tid >> 6;
  const int q = lane >> 4;
  const int c15 = lane & 15;
  const int b0 = blockIdx.x * BC;

  // resident weight fragments, prescaled: r,z by log2e; n by 2*log2e
  bhalf8 whh[3][4];
  bhalf8 wih[3][2];
#pragma unroll
  for (int g = 0; g < 3; ++g) {
    const float sc = (g == 2) ? 2.0f * L2E : L2E;
    const int grow = g * HH + wv * 16 + c15;
#pragma unroll
    for (int kt = 0; kt < 4; ++kt)
      whh[g][kt] = packrow8s(Whh + grow * HH + kt * 32 + q * 8, sc);
#pragma unroll
    for (int kt = 0; kt < 2; ++kt)
      wih[g][kt] = packrow8s(Wih + grow * II + kt * 32 + q * 8, sc);
  }

  f32x4 bias_r, bias_z, bias_hn, bias_xn;
#pragma unroll
  for (int r = 0; r < 4; ++r) {
    const int d = wv * 16 + q * 4 + r;
    bias_r[r]  = (bih[d] + bhh[d]) * L2E;
    bias_z[r]  = (bih[HH + d] + bhh[HH + d]) * L2E;
    bias_xn[r] = bih[2 * HH + d] * (2.0f * L2E);
    bias_hn[r] = bhh[2 * HH + d] * (2.0f * L2E);
  }

  for (int i = tid; i < BC * HROW; i += NTHR) hsh[0][i] = 0;

  // per-thread staging geometry: thread covers (tpA, bs, g8) and (tpA+4, bs, g8)
  const int tpA = tid >> 7, bs = (tid >> 3) & 15, g8 = tid & 7;
  const float* xsrcA = xin + (size_t)(b0 + bs) * (TT * II) + tpA * II + g8 * 8;
  short* xstA = &xsh[0][tpA][bs * XROW + g8 * 8];

  float4 xl0, xl1, xl2, xl3;
  // stage chunk 0
  {
    float4 a0 = *(const float4*)(xsrcA);
    float4 a1 = *(const float4*)(xsrcA + 4);
    float4 a2 = *(const float4*)(xsrcA + 4 * II);
    float4 a3 = *(const float4*)(xsrcA + 4 * II + 4);
    union { bhalf8 v; unsigned u[4]; } cv;
    cv.u[0] = cvtpk(a0.x, a0.y); cv.u[1] = cvtpk(a0.z, a0.w);
    cv.u[2] = cvtpk(a1.x, a1.y); cv.u[3] = cvtpk(a1.z, a1.w);
    *(bhalf8*)xstA = cv.v;
    cv.u[0] = cvtpk(a2.x, a2.y); cv.u[1] = cvtpk(a2.z, a2.w);
    cv.u[2] = cvtpk(a3.x, a3.y); cv.u[3] = cvtpk(a3.z, a3.w);
    *(bhalf8*)(xstA + 4 * (BC * XROW)) = cv.v;
  }
  __syncthreads();

  const short* hrd0 = &hsh[0][c15 * HROW];
  const short* hrd1 = &hsh[1][c15 * HROW];
  short* hw0 = &hsh[1][c15 * HROW + wv * 16 + q * 4];  // write when t even
  short* hw1 = &hsh[0][c15 * HROW + wv * 16 + q * 4];  // write when t odd
  const short* xbase = &xsh[0][0][c15 * XROW];

  f32x4 hprev = {0.f, 0.f, 0.f, 0.f};
  f32x4 aR, aZ, aHN, aXN, bR, bZ, bHN, bXN;

  // prologue: fill set A for t=0
  {
    const short* xrow = xbase;
    bhalf8 xf0 = *(const bhalf8*)(xrow + q * 8);
    bhalf8 xf1 = *(const bhalf8*)(xrow + 32 + q * 8);
    aR  = bias_r;
    aR  = mfma16(wih[0][0], xf0, aR);  aR  = mfma16(wih[0][1], xf1, aR);
    aZ  = bias_z;
    aZ  = mfma16(wih[1][0], xf0, aZ);  aZ  = mfma16(wih[1][1], xf1, aZ);
    aXN = bias_xn;
    aXN = mfma16(wih[2][0], xf0, aXN); aXN = mfma16(wih[2][1], xf1, aXN);
    aHN = bias_hn;
  }

#pragma unroll 1
  for (int c = 0; c < TT / CHUNK; ++c) {
    const int more = (c + 1 < TT / CHUNK);
    DOSTEP(0, aR, aZ, aHN, aXN, bR, bZ, bHN, bXN)
    DOSTEP(1, bR, bZ, bHN, bXN, aR, aZ, aHN, aXN)
    DOSTEP(2, aR, aZ, aHN, aXN, bR, bZ, bHN, bXN)
    DOSTEP(3, bR, bZ, bHN, bXN, aR, aZ, aHN, aXN)
    DOSTEP(4, aR, aZ, aHN, aXN, bR, bZ, bHN, bXN)
    DOSTEP(5, bR, bZ, bHN, bXN, aR, aZ, aHN, aXN)
    DOSTEP(6, aR, aZ, aHN, aXN, bR, bZ, bHN, bXN)
    DOSTEP(7, bR, bZ, bHN, bXN, aR, aZ, aHN, aXN)
  }

  // FC head: h_T is in hsh[0] (t=1024 parity 0)
  for (int idx = tid; idx < BC * 51; idx += NTHR) {
    const int bb = idx / 51;
    const int o = idx - bb * 51;
    const float* wf = Wfc + o * HH;
    const short* hr = &hsh[0][bb * HROW];
    float s = bfc[o];
#pragma unroll
    for (int d = 0; d < HH; d += 4) {
      const float4 wvv = *(const float4*)(wf + d);
      s += bf2f(hr[d]) * wvv.x + bf2f(hr[d + 1]) * wvv.y
         + bf2f(hr[d + 2]) * wvv.z + bf2f(hr[d + 3]) * wvv.w;
    }
    out[(size_t)(b0 + bb) * 51 + o] = s;
  }
}

extern "C" void kernel_launch(void* const* d_in, const int* in_sizes, int n_in,
                              void* d_out, int out_size, void* d_ws, size_t ws_size,
                              hipStream_t stream) {
  const float* xin = (const float*)d_in[0];
  const float* Wih = (const float*)d_in[1];
  const float* Whh = (const float*)d_in[2];
  const float* bih = (const float*)d_in[3];
  const float* bhh = (const float*)d_in[4];
  const float* Wfc = (const float*)d_in[5];
  const float* bfc = (const float*)d_in[6];
  float* o = (float*)d_out;
  hipLaunchKernelGGL(gru_fused, dim3(BATCH / BC), dim3(NTHR), 0, stream,
                     xin, Wih, Whh, bih, bhh, Wfc, bfc, o);
}

// Round 5
// 584.875 us; speedup vs baseline: 4.4099x; 1.0408x over previous
//
#include <hip/hip_runtime.h>
#include <hip/hip_bf16.h>

#define TT    1024
#define BATCH 512
#define HH    128
#define II    64
#define BC    16
#define NTHR  512
#define CHUNK 8
#define XROW  72   // shorts per x row: 64 data + 8 pad
#define HROW  136  // shorts per h row: 128 data + 8 pad
#define L2E   1.4426950408889634f

typedef __attribute__((ext_vector_type(8))) short bhalf8;
typedef __attribute__((ext_vector_type(4))) short bhalf4;
typedef __attribute__((ext_vector_type(4))) float f32x4;

static __device__ __forceinline__ unsigned cvtpk(float lo, float hi) {
  unsigned r;
  asm("v_cvt_pk_bf16_f32 %0, %1, %2" : "=v"(r) : "v"(lo), "v"(hi));
  return r;
}
static __device__ __forceinline__ float bf2f(short s) {
  return __builtin_bit_cast(float, ((unsigned)(unsigned short)s) << 16);
}
static __device__ __forceinline__ f32x4 mfma16(bhalf8 a, bhalf8 b, f32x4 c) {
  return __builtin_amdgcn_mfma_f32_16x16x32_bf16(a, b, c, 0, 0, 0);
}
static __device__ __forceinline__ bhalf8 packrow8s(const float* p, float s) {
  union { bhalf8 v; unsigned u[4]; } cv;
  cv.u[0] = cvtpk(p[0] * s, p[1] * s);
  cv.u[1] = cvtpk(p[2] * s, p[3] * s);
  cv.u[2] = cvtpk(p[4] * s, p[5] * s);
  cv.u[3] = cvtpk(p[6] * s, p[7] * s);
  return cv.v;
}
// barrier without vmcnt drain; lgkmcnt(0) orders LDS
static __device__ __forceinline__ void bar_lgkm() {
  asm volatile("s_waitcnt lgkmcnt(0)\n\ts_barrier" ::: "memory");
}

// Step schedule (issue-order = overlap plan):
//   12 h-MFMA (3 chains: ar, az, ahn) -> matrix pipe busy ~466cy/SIMD
//   gates split by chain, INTERLEAVED with next step's 6 x-MFMAs so the
//   x-MFMAs slot into the draining matrix pipe while VALU/trans runs:
//   rg(dep ar) | 2 x-MFMA | zg(dep az) | 2 x-MFMA | n/h(dep ahn) | 2 x-MFMA
#define DOSTEP(TP, AR, AZ, AXN, BR, BZ, BXN)                                    \
  {                                                                             \
    constexpr int tp = (TP);                                                    \
    const short* hrow = (tp & 1) ? hrd1 : hrd0;                                 \
    bhalf8 hf0 = *(const bhalf8*)(hrow + q * 8);                                \
    bhalf8 hf1 = *(const bhalf8*)(hrow + 32 + q * 8);                           \
    bhalf8 hf2 = *(const bhalf8*)(hrow + 64 + q * 8);                           \
    bhalf8 hf3 = *(const bhalf8*)(hrow + 96 + q * 8);                           \
    /* x frags for t+1 (issue reads early; latency hides under h-MFMAs) */      \
    const int nb2 = (tp == 7) ? ((c + 1) & 1) : (c & 1);                        \
    const short* xrow = xbase + nb2 * (CHUNK * BC * XROW)                       \
                              + ((tp + 1) & 7) * (BC * XROW);                   \
    bhalf8 xf0 = *(const bhalf8*)(xrow + q * 8);                                \
    bhalf8 xf1 = *(const bhalf8*)(xrow + 32 + q * 8);                           \
    if (tp == 0 && more) { /* issue next-chunk global loads */                  \
      const float* sA = xsrcA + (size_t)(c + 1) * (CHUNK * II);                 \
      xl0 = *(const float4*)(sA);                                               \
      xl1 = *(const float4*)(sA + 4);                                           \
      xl2 = *(const float4*)(sA + 4 * II);                                      \
      xl3 = *(const float4*)(sA + 4 * II + 4);                                  \
    }                                                                           \
    /* h-side MFMAs, grouped by acc chain (ar first -> rg can start early) */   \
    AR  = mfma16(whh[0][0], hf0, AR);  AR  = mfma16(whh[0][1], hf1, AR);        \
    AR  = mfma16(whh[0][2], hf2, AR);  AR  = mfma16(whh[0][3], hf3, AR);        \
    AZ  = mfma16(whh[1][0], hf0, AZ);  AZ  = mfma16(whh[1][1], hf1, AZ);        \
    AZ  = mfma16(whh[1][2], hf2, AZ);  AZ  = mfma16(whh[1][3], hf3, AZ);        \
    f32x4 ahn = mfma16(whh[2][0], hf0, bias_hn);                                \
    ahn = mfma16(whh[2][1], hf1, ahn);                                          \
    ahn = mfma16(whh[2][2], hf2, ahn);                                          \
    ahn = mfma16(whh[2][3], hf3, ahn);                                          \
    /* ---- gates chain r (waits only on AR) ---- */                            \
    float rg0, rg1, rg2, rg3;                                                   \
    rg0 = __builtin_amdgcn_rcpf(1.0f + __builtin_amdgcn_exp2f(-AR[0]));         \
    rg1 = __builtin_amdgcn_rcpf(1.0f + __builtin_amdgcn_exp2f(-AR[1]));         \
    rg2 = __builtin_amdgcn_rcpf(1.0f + __builtin_amdgcn_exp2f(-AR[2]));         \
    rg3 = __builtin_amdgcn_rcpf(1.0f + __builtin_amdgcn_exp2f(-AR[3]));         \
    /* x-MFMAs for t+1, r-gate (independent; fills matrix pipe under VALU) */   \
    BR = mfma16(wih[0][0], xf0, bias_r);                                        \
    BR = mfma16(wih[0][1], xf1, BR);                                            \
    /* ---- gates chain z ---- */                                               \
    float zg0, zg1, zg2, zg3;                                                   \
    zg0 = __builtin_amdgcn_rcpf(1.0f + __builtin_amdgcn_exp2f(-AZ[0]));         \
    zg1 = __builtin_amdgcn_rcpf(1.0f + __builtin_amdgcn_exp2f(-AZ[1]));         \
    zg2 = __builtin_amdgcn_rcpf(1.0f + __builtin_amdgcn_exp2f(-AZ[2]));         \
    zg3 = __builtin_amdgcn_rcpf(1.0f + __builtin_amdgcn_exp2f(-AZ[3]));         \
    BZ = mfma16(wih[1][0], xf0, bias_z);                                        \
    BZ = mfma16(wih[1][1], xf1, BZ);                                            \
    /* ---- gates chain n + h update (waits on ahn) ---- */                     \
    {                                                                           \
      const float na0 = fmaf(rg0, ahn[0], AXN[0]);                              \
      const float na1 = fmaf(rg1, ahn[1], AXN[1]);                              \
      const float na2 = fmaf(rg2, ahn[2], AXN[2]);                              \
      const float na3 = fmaf(rg3, ahn[3], AXN[3]);                              \
      const float ng0 = fmaf(-2.0f,                                             \
          __builtin_amdgcn_rcpf(__builtin_amdgcn_exp2f(na0) + 1.0f), 1.0f);     \
      const float ng1 = fmaf(-2.0f,                                             \
          __builtin_amdgcn_rcpf(__builtin_amdgcn_exp2f(na1) + 1.0f), 1.0f);     \
      const float ng2 = fmaf(-2.0f,                                             \
          __builtin_amdgcn_rcpf(__builtin_amdgcn_exp2f(na2) + 1.0f), 1.0f);     \
      const float ng3 = fmaf(-2.0f,                                             \
          __builtin_amdgcn_rcpf(__builtin_amdgcn_exp2f(na3) + 1.0f), 1.0f);     \
      hprev[0] = fmaf(zg0, hprev[0] - ng0, ng0);                                \
      hprev[1] = fmaf(zg1, hprev[1] - ng1, ng1);                                \
      hprev[2] = fmaf(zg2, hprev[2] - ng2, ng2);                                \
      hprev[3] = fmaf(zg3, hprev[3] - ng3, ng3);                                \
    }                                                                           \
    BXN = mfma16(wih[2][0], xf0, bias_xn);                                      \
    BXN = mfma16(wih[2][1], xf1, BXN);                                          \
    {                                                                           \
      union { bhalf4 v; unsigned u[2]; } hp;                                    \
      hp.u[0] = cvtpk(hprev[0], hprev[1]);                                      \
      hp.u[1] = cvtpk(hprev[2], hprev[3]);                                      \
      *(bhalf4*)((tp & 1) ? hw1 : hw0) = hp.v;                                  \
    }                                                                           \
    if (tp == 4 && more) { /* write staged chunk into other x buffer */         \
      short* xd = xstA + ((c + 1) & 1) * (CHUNK * BC * XROW);                   \
      union { bhalf8 v; unsigned u[4]; } cv;                                    \
      cv.u[0] = cvtpk(xl0.x, xl0.y); cv.u[1] = cvtpk(xl0.z, xl0.w);             \
      cv.u[2] = cvtpk(xl1.x, xl1.y); cv.u[3] = cvtpk(xl1.z, xl1.w);             \
      *(bhalf8*)xd = cv.v;                                                      \
      cv.u[0] = cvtpk(xl2.x, xl2.y); cv.u[1] = cvtpk(xl2.z, xl2.w);             \
      cv.u[2] = cvtpk(xl3.x, xl3.y); cv.u[3] = cvtpk(xl3.z, xl3.w);             \
      *(bhalf8*)(xd + 4 * (BC * XROW)) = cv.v;                                  \
    }                                                                           \
    bar_lgkm();                                                                 \
  }

__global__ __launch_bounds__(NTHR) __attribute__((amdgpu_waves_per_eu(2, 2)))
void gru_fused(
    const float* __restrict__ xin, const float* __restrict__ Wih,
    const float* __restrict__ Whh, const float* __restrict__ bih,
    const float* __restrict__ bhh, const float* __restrict__ Wfc,
    const float* __restrict__ bfc, float* __restrict__ out)
{
  __shared__ short xsh[2][CHUNK][BC * XROW];
  __shared__ short hsh[2][BC * HROW];

  const int tid = threadIdx.x;
  const int lane = tid & 63;
  const int wv = tid >> 6;
  const int q = lane >> 4;
  const int c15 = lane & 15;
  const int b0 = blockIdx.x * BC;

  // resident weight fragments, prescaled: r,z by log2e; n by 2*log2e
  bhalf8 whh[3][4];
  bhalf8 wih[3][2];
#pragma unroll
  for (int g = 0; g < 3; ++g) {
    const float sc = (g == 2) ? 2.0f * L2E : L2E;
    const int grow = g * HH + wv * 16 + c15;
#pragma unroll
    for (int kt = 0; kt < 4; ++kt)
      whh[g][kt] = packrow8s(Whh + grow * HH + kt * 32 + q * 8, sc);
#pragma unroll
    for (int kt = 0; kt < 2; ++kt)
      wih[g][kt] = packrow8s(Wih + grow * II + kt * 32 + q * 8, sc);
  }

  f32x4 bias_r, bias_z, bias_hn, bias_xn;
#pragma unroll
  for (int r = 0; r < 4; ++r) {
    const int d = wv * 16 + q * 4 + r;
    bias_r[r]  = (bih[d] + bhh[d]) * L2E;
    bias_z[r]  = (bih[HH + d] + bhh[HH + d]) * L2E;
    bias_xn[r] = bih[2 * HH + d] * (2.0f * L2E);
    bias_hn[r] = bhh[2 * HH + d] * (2.0f * L2E);
  }

  for (int i = tid; i < BC * HROW; i += NTHR) hsh[0][i] = 0;

  const int tpA = tid >> 7, bs = (tid >> 3) & 15, g8 = tid & 7;
  const float* xsrcA = xin + (size_t)(b0 + bs) * (TT * II) + tpA * II + g8 * 8;
  short* xstA = &xsh[0][tpA][bs * XROW + g8 * 8];

  float4 xl0, xl1, xl2, xl3;
  // stage chunk 0
  {
    float4 a0 = *(const float4*)(xsrcA);
    float4 a1 = *(const float4*)(xsrcA + 4);
    float4 a2 = *(const float4*)(xsrcA + 4 * II);
    float4 a3 = *(const float4*)(xsrcA + 4 * II + 4);
    union { bhalf8 v; unsigned u[4]; } cv;
    cv.u[0] = cvtpk(a0.x, a0.y); cv.u[1] = cvtpk(a0.z, a0.w);
    cv.u[2] = cvtpk(a1.x, a1.y); cv.u[3] = cvtpk(a1.z, a1.w);
    *(bhalf8*)xstA = cv.v;
    cv.u[0] = cvtpk(a2.x, a2.y); cv.u[1] = cvtpk(a2.z, a2.w);
    cv.u[2] = cvtpk(a3.x, a3.y); cv.u[3] = cvtpk(a3.z, a3.w);
    *(bhalf8*)(xstA + 4 * (BC * XROW)) = cv.v;
  }
  __syncthreads();

  const short* hrd0 = &hsh[0][c15 * HROW];
  const short* hrd1 = &hsh[1][c15 * HROW];
  short* hw0 = &hsh[1][c15 * HROW + wv * 16 + q * 4];  // write when t even
  short* hw1 = &hsh[0][c15 * HROW + wv * 16 + q * 4];  // write when t odd
  const short* xbase = &xsh[0][0][c15 * XROW];

  f32x4 hprev = {0.f, 0.f, 0.f, 0.f};
  f32x4 aR, aZ, aXN, bR, bZ, bXN;

  // prologue: fill set A for t=0
  {
    const short* xrow = xbase;
    bhalf8 xf0 = *(const bhalf8*)(xrow + q * 8);
    bhalf8 xf1 = *(const bhalf8*)(xrow + 32 + q * 8);
    aR  = mfma16(wih[0][0], xf0, bias_r);
    aR  = mfma16(wih[0][1], xf1, aR);
    aZ  = mfma16(wih[1][0], xf0, bias_z);
    aZ  = mfma16(wih[1][1], xf1, aZ);
    aXN = mfma16(wih[2][0], xf0, bias_xn);
    aXN = mfma16(wih[2][1], xf1, aXN);
  }

#pragma unroll 1
  for (int c = 0; c < TT / CHUNK; ++c) {
    const int more = (c + 1 < TT / CHUNK);
    DOSTEP(0, aR, aZ, aXN, bR, bZ, bXN)
    DOSTEP(1, bR, bZ, bXN, aR, aZ, aXN)
    DOSTEP(2, aR, aZ, aXN, bR, bZ, bXN)
    DOSTEP(3, bR, bZ, bXN, aR, aZ, aXN)
    DOSTEP(4, aR, aZ, aXN, bR, bZ, bXN)
    DOSTEP(5, bR, bZ, bXN, aR, aZ, aXN)
    DOSTEP(6, aR, aZ, aXN, bR, bZ, bXN)
    DOSTEP(7, bR, bZ, bXN, aR, aZ, aXN)
  }

  // FC head: h_T is in hsh[0]
  for (int idx = tid; idx < BC * 51; idx += NTHR) {
    const int bb = idx / 51;
    const int o = idx - bb * 51;
    const float* wf = Wfc + o * HH;
    const short* hr = &hsh[0][bb * HROW];
    float s = bfc[o];
#pragma unroll
    for (int d = 0; d < HH; d += 4) {
      const float4 wvv = *(const float4*)(wf + d);
      s += bf2f(hr[d]) * wvv.x + bf2f(hr[d + 1]) * wvv.y
         + bf2f(hr[d + 2]) * wvv.z + bf2f(hr[d + 3]) * wvv.w;
    }
    out[(size_t)(b0 + bb) * 51 + o] = s;
  }
}

extern "C" void kernel_launch(void* const* d_in, const int* in_sizes, int n_in,
                              void* d_out, int out_size, void* d_ws, size_t ws_size,
                              hipStream_t stream) {
  const float* xin = (const float*)d_in[0];
  const float* Wih = (const float*)d_in[1];
  const float* Whh = (const float*)d_in[2];
  const float* bih = (const float*)d_in[3];
  const float* bhh = (const float*)d_in[4];
  const float* Wfc = (const float*)d_in[5];
  const float* bfc = (const float*)d_in[6];
  float* o = (float*)d_out;
  hipLaunchKernelGGL(gru_fused, dim3(BATCH / BC), dim3(NTHR), 0, stream,
                     xin, Wih, Whh, bih, bhh, Wfc, bfc, o);
}